// Round 1
// baseline (17383.842 us; speedup 1.0000x reference)
//
#include <hip/hip_runtime.h>
#include <hip/hip_bf16.h>

typedef __bf16 bf16x8 __attribute__((ext_vector_type(8)));
typedef float f32x4 __attribute__((ext_vector_type(4)));

#define BB   128
#define SS   512
#define DD   128
#define HH   1024
#define OO   64
#define IIN  257

// scan decomposition: 2 batch groups x 128 blocks; each block owns 8 h-cols (32 gate cols)
#define NGROUP 2
#define GBLK   128
#define MG     64     // batch rows per group
#define NC     32     // gate cols per block
#define KK_H   32     // 1024/32
#define KK_X   9      // 288/32 (257 padded to 288, ti folded in at k=256)

#define XTP_SLAB  18432    // 4mt * 9kk * 64lane * 8 bf16 per (t,p)
#define HBUF_SLAB 65536    // 4mt * 32kk * 64lane * 8 bf16 per (p,buf)

// ws layout (bytes): [0,512) barrier counters | [512, 512+512K) hbuf (4 slabs)
// | hlast fp32 128x1024 | xtp bf16 1024 slabs
#define WS_HBUF  512
#define WS_HLAST 524800
#define WS_XTP   1049088

__global__ void prepack_kernel(const float* __restrict__ x, const float* __restrict__ mask,
                               const float* __restrict__ ti, __bf16* __restrict__ xtp) {
  int idx = blockIdx.x * 256 + threadIdx.x;        // 1024 slabs * 18432
  int slab = idx / XTP_SLAB;
  int rem  = idx - slab * XTP_SLAB;
  int p = slab & 1, t = slab >> 1;
  int j = rem & 7, l = (rem >> 3) & 63;
  int t2 = rem >> 9;                               // 0..35
  int kk = t2 % 9, mt = t2 / 9;
  int b = p * MG + mt * 16 + (l & 15);
  int k = kk * 32 + ((l >> 4) << 3) + j;
  float v;
  if (k < 128)       v = x[(b * SS + t) * DD + k];
  else if (k < 256)  v = mask[(b * SS + t) * DD + (k - 128)];
  else if (k == 256) v = ti[b * SS + t];
  else               v = 0.f;
  xtp[idx] = (__bf16)v;
}

__device__ __forceinline__ float sigmoid_f(float v) { return 1.f / (1.f + __expf(-v)); }
__device__ __forceinline__ float tanh_f(float v)    { return 1.f - 2.f / (__expf(2.f * v) + 1.f); }

__launch_bounds__(256, 1)
__global__ void lstm_scan(const float* __restrict__ W_ih, const float* __restrict__ W_hh,
                          const float* __restrict__ b_ih, const float* __restrict__ b_hh,
                          const __bf16* __restrict__ xtp, __bf16* __restrict__ hbuf,
                          float* __restrict__ hlast, unsigned int* __restrict__ cnt) {
  // fragment-packed weights, resident for all 512 steps
  __shared__ __bf16 whh_lds[2 * KK_H * 512];   // 64 KB : [nt][kk][lane][j]
  __shared__ __bf16 wih_lds[2 * KK_X * 512];   // 18 KB
  __shared__ float  bias_lds[NC];
  __shared__ float  gstage[64 * 36];           // 9 KB, padded stride 36
  __shared__ float  c_lds[512];                // cell state [m][j]

  const int tid = threadIdx.x;
  const int bid = blockIdx.x;
  const int p   = bid >> 7;        // batch group
  const int bIG = bid & 127;
  const int j0  = bIG * 8;         // owned h-columns [j0, j0+8)

  // ---- one-time init: pack W_hh / W_ih slices into LDS in B-fragment order ----
  for (int e = tid; e < 2 * KK_H * 512; e += 256) {
    int j = e & 7, l = (e >> 3) & 63, kk = (e >> 9) & 31, nt = e >> 14;
    int n = nt * 16 + (l & 15);                       // n = gate*8 + jj
    int col = ((n >> 3) << 10) + j0 + (n & 7);        // gate*1024 + j0 + jj
    int k = kk * 32 + ((l >> 4) << 3) + j;
    whh_lds[e] = (__bf16)W_hh[col * HH + k];
  }
  for (int e = tid; e < 2 * KK_X * 512; e += 256) {
    int j = e & 7, l = (e >> 3) & 63;
    int t2 = e >> 9;                                  // 0..17
    int kk = t2 % 9, nt = t2 / 9;
    int n = nt * 16 + (l & 15);
    int col = ((n >> 3) << 10) + j0 + (n & 7);
    int k = kk * 32 + ((l >> 4) << 3) + j;
    wih_lds[e] = (k < IIN) ? (__bf16)W_ih[col * IIN + k] : (__bf16)0.f;
  }
  if (tid < NC) {
    int n = tid;
    int col = ((n >> 3) << 10) + j0 + (n & 7);
    bias_lds[n] = b_ih[col] + b_hh[col];
  }
  for (int e = tid; e < 512; e += 256) c_lds[e] = 0.f;
  __syncthreads();

  const int w = tid >> 6;    // wave id = M-tile
  const int l = tid & 63;
  unsigned int* mycnt = cnt + p * 64;   // separate cache lines per group

  for (int t = 0; t < SS; ++t) {
    const int rb = t & 1, wb = rb ^ 1;
    const __bf16* hb  = hbuf + (p * 2 + rb) * HBUF_SLAB + w * (KK_H * 512);
    const __bf16* xb  = xtp + (size_t)(t * 2 + p) * XTP_SLAB + w * (KK_X * 512);
    f32x4 acc0 = {0.f, 0.f, 0.f, 0.f};
    f32x4 acc1 = {0.f, 0.f, 0.f, 0.f};

    // x-part: K = 288 (includes ti at k=256, zero-padded above 257)
    #pragma unroll
    for (int kk = 0; kk < KK_X; ++kk) {
      bf16x8 a  = *(const bf16x8*)(xb + kk * 512 + l * 8);
      bf16x8 b0 = *(const bf16x8*)(wih_lds + kk * 512 + l * 8);
      bf16x8 b1 = *(const bf16x8*)(wih_lds + KK_X * 512 + kk * 512 + l * 8);
      acc0 = __builtin_amdgcn_mfma_f32_16x16x32_bf16(a, b0, acc0, 0, 0, 0);
      acc1 = __builtin_amdgcn_mfma_f32_16x16x32_bf16(a, b1, acc1, 0, 0, 0);
    }
    // h-part: K = 1024, A streamed from global (fragment-packed), B from LDS
    #pragma unroll 8
    for (int kk = 0; kk < KK_H; ++kk) {
      bf16x8 a  = *(const bf16x8*)(hb + kk * 512 + l * 8);
      bf16x8 b0 = *(const bf16x8*)(whh_lds + kk * 512 + l * 8);
      bf16x8 b1 = *(const bf16x8*)(whh_lds + KK_H * 512 + kk * 512 + l * 8);
      acc0 = __builtin_amdgcn_mfma_f32_16x16x32_bf16(a, b0, acc0, 0, 0, 0);
      acc1 = __builtin_amdgcn_mfma_f32_16x16x32_bf16(a, b1, acc1, 0, 0, 0);
    }

    // stage accumulators (C-layout: col=lane&15, row=(lane>>4)*4+r) to LDS
    {
      int q = l >> 4, n = l & 15;
      float bi0 = bias_lds[n], bi1 = bias_lds[16 + n];
      #pragma unroll
      for (int r = 0; r < 4; ++r) {
        int m = w * 16 + q * 4 + r;
        gstage[m * 36 + n]      = acc0[r] + bi0;
        gstage[m * 36 + 16 + n] = acc1[r] + bi1;
      }
    }
    __syncthreads();

    // gate phase: 512 (m,j) pairs, 2 per thread
    __bf16* hw = hbuf + (p * 2 + wb) * HBUF_SLAB;
    #pragma unroll
    for (int e = tid; e < 512; e += 256) {
      int m = e >> 3, j = e & 7;
      float gi = gstage[m * 36 + j];
      float gf = gstage[m * 36 + 8 + j];
      float gg = gstage[m * 36 + 16 + j];
      float go = gstage[m * 36 + 24 + j];
      float i_ = sigmoid_f(gi);
      float f_ = sigmoid_f(gf);
      float g_ = tanh_f(gg);
      float o_ = sigmoid_f(go);
      float c  = f_ * c_lds[e] + i_ * g_;
      c_lds[e] = c;
      float h  = o_ * tanh_f(c);
      // write h into next-step A-fragment-packed buffer
      int k = j0 + j;
      int mt = m >> 4, nn = m & 15, kk2 = k >> 5, q2 = (k >> 3) & 3, jj = k & 7;
      hw[((mt * 32 + kk2) * 64 + q2 * 16 + nn) * 8 + jj] = (__bf16)h;
      if (t == SS - 1) hlast[(p * MG + m) * HH + k] = h;
    }

    // inter-block barrier (per group, monotone counter, double-buffered h => 1/step)
    __threadfence();
    __syncthreads();
    if (t < SS - 1) {
      if (tid == 0) {
        __hip_atomic_fetch_add(mycnt, 1u, __ATOMIC_RELEASE, __HIP_MEMORY_SCOPE_AGENT);
        unsigned int target = (unsigned int)(GBLK * (t + 1));
        while (__hip_atomic_load(mycnt, __ATOMIC_ACQUIRE, __HIP_MEMORY_SCOPE_AGENT) < target) {
          __builtin_amdgcn_s_sleep(1);
        }
      }
      __syncthreads();
    }
  }
}

__global__ void fc_kernel(const float* __restrict__ hlast, const float* __restrict__ W_fc,
                          const float* __restrict__ b_fc, float* __restrict__ out) {
  int b = blockIdx.x;            // 128
  int t = threadIdx.x;           // 256
  int o = t >> 2, part = t & 3;
  const float* hr = hlast + b * HH;
  const float* wr = W_fc + o * HH;
  float s = 0.f;
  #pragma unroll 4
  for (int k0 = part * 4; k0 < HH; k0 += 16) {
    float4 hv = *(const float4*)(hr + k0);
    float4 wv = *(const float4*)(wr + k0);
    s += hv.x * wv.x + hv.y * wv.y + hv.z * wv.z + hv.w * wv.w;
  }
  s += __shfl_xor(s, 1);
  s += __shfl_xor(s, 2);
  if (part == 0) out[b * OO + o] = s + b_fc[o];
}

extern "C" void kernel_launch(void* const* d_in, const int* in_sizes, int n_in,
                              void* d_out, int out_size, void* d_ws, size_t ws_size,
                              hipStream_t stream) {
  const float* x    = (const float*)d_in[0];
  const float* mask = (const float*)d_in[1];
  const float* ti   = (const float*)d_in[2];
  const float* W_ih = (const float*)d_in[3];
  const float* W_hh = (const float*)d_in[4];
  const float* b_ih = (const float*)d_in[5];
  const float* b_hh = (const float*)d_in[6];
  const float* W_fc = (const float*)d_in[7];
  const float* b_fc = (const float*)d_in[8];
  float* out = (float*)d_out;

  char* ws = (char*)d_ws;
  unsigned int* cnt = (unsigned int*)ws;
  __bf16* hbuf  = (__bf16*)(ws + WS_HBUF);
  float*  hlast = (float*)(ws + WS_HLAST);
  __bf16* xtp   = (__bf16*)(ws + WS_XTP);

  // zero barrier counters + h double-buffers (ws is poisoned 0xAA before each launch)
  hipMemsetAsync(ws, 0, WS_HLAST, stream);

  prepack_kernel<<<(1024 * XTP_SLAB) / 256, 256, 0, stream>>>(x, mask, ti, xtp);
  lstm_scan<<<NGROUP * GBLK, 256, 0, stream>>>(W_ih, W_hh, b_ih, b_hh, xtp, hbuf, hlast, cnt);
  fc_kernel<<<BB, 256, 0, stream>>>(hlast, W_fc, b_fc, out);
}